// Round 12
// baseline (508.402 us; speedup 1.0000x reference)
//
#include <hip/hip_runtime.h>
#include <math.h>

typedef unsigned short ushort;
typedef unsigned int uint;
typedef __attribute__((ext_vector_type(8))) short short8;
typedef __attribute__((ext_vector_type(4))) float f32x4;
typedef __attribute__((ext_vector_type(4))) ushort us4;

constexpr int BS = 2, C_IN = 8, CTX = 1024, TGT = 96;
constexpr int DM = 256, NH = 16, DFF = 1024, NL = 4;
constexpr int NF = 256, TOTAL = 320;
constexpr int NB = 16;
constexpr int DK = 16;
constexpr float EPS = 1e-5f;
constexpr float SCALE = 0.25f;
constexpr int KHEAD = DM * TOTAL;  // 81920
constexpr int M = NB * TOTAL;      // 5120

__device__ __forceinline__ ushort f2b(float x) {
    uint u = __float_as_uint(x);
    u += 0x7fff + ((u >> 16) & 1);
    return (ushort)(u >> 16);
}
__device__ __forceinline__ float bu2f(ushort x) { return __uint_as_float(((uint)x) << 16); }
__device__ __forceinline__ float lo2f(uint p) { return __uint_as_float(p << 16); }
__device__ __forceinline__ float hi2f(uint p) { return __uint_as_float(p & 0xffff0000u); }
__device__ __forceinline__ uint pack2(float a, float b) { return (uint)f2b(a) | ((uint)f2b(b) << 16); }

// ---------------- weight conversions + RevIN in ONE launch; 1D grid decode ----------------
// blocks: [0,1024) sq QKV/O; [1024,2048) F1; [2048,3072) F2; [3072,10752) head; [10752,10768) RevIN
__global__ void k_prep(const float* __restrict__ WQ, const float* __restrict__ WK,
                       const float* __restrict__ WV, const float* __restrict__ WO,
                       const float* __restrict__ F1, const float* __restrict__ F2,
                       const float* __restrict__ Wh,
                       ushort* __restrict__ Wtqkv, ushort* __restrict__ WtO,
                       ushort* __restrict__ Ft1, ushort* __restrict__ Ft2,
                       ushort* __restrict__ WhT2,
                       const float* __restrict__ z, const float* __restrict__ rw,
                       const float* __restrict__ rb, float* __restrict__ zn,
                       float* __restrict__ meanv, float* __restrict__ stdv) {
    __shared__ ushort tile[32][33];
    __shared__ float rr1[16], rr2[16], bcast[2];
    int i = blockIdx.x;
    int tx = threadIdx.x, ty = threadIdx.y;
    if (i < 1024) {
        int zz = i >> 6, w = zz >> 2, l = zz & 3;
        const float* src = (w == 0 ? WQ : (w == 1 ? WK : (w == 2 ? WV : WO))) + l * 65536;
        ushort* dst = (w < 3) ? (Wtqkv + (size_t)l * 768 * 256 + w * 256 * 256)
                              : (WtO + (size_t)l * 65536);
        int c0 = (i & 7) * 32, r0 = ((i >> 3) & 7) * 32;
        tile[ty][tx] = f2b(src[(r0 + ty) * 256 + c0 + tx]);
        __syncthreads();
        dst[(c0 + ty) * 256 + r0 + tx] = tile[tx][ty];
    } else if (i < 2048) {
        int j = i - 1024, l = j >> 8;
        const float* src = F1 + (size_t)l * 262144;
        ushort* dst = Ft1 + (size_t)l * 262144;
        int c0 = (j & 31) * 32, r0 = ((j >> 5) & 7) * 32;
        tile[ty][tx] = f2b(src[(r0 + ty) * 1024 + c0 + tx]);
        __syncthreads();
        dst[(c0 + ty) * 256 + r0 + tx] = tile[tx][ty];
    } else if (i < 3072) {
        int j = i - 2048, l = j >> 8;
        const float* src = F2 + (size_t)l * 262144;
        ushort* dst = Ft2 + (size_t)l * 262144;
        int c0 = (j & 7) * 32, r0 = ((j >> 3) & 31) * 32;
        tile[ty][tx] = f2b(src[(r0 + ty) * 256 + c0 + tx]);
        __syncthreads();
        dst[(c0 + ty) * 1024 + r0 + tx] = tile[tx][ty];
    } else if (i < 10752) {
        int j = i - 3072;
        int t0 = (j % 3) * 32, rest = j / 3;
        int d0 = (rest & 7) * 32, pp = rest >> 3;
        tile[ty][tx] = f2b(Wh[((size_t)(d0 + ty) * 320 + pp) * 96 + t0 + tx]);
        __syncthreads();
        WhT2[(size_t)(t0 + ty) * KHEAD + pp * 256 + d0 + tx] = tile[tx][ty];
    } else {
        int bc = i - 10752;
        int tid = ty * 32 + tx;       // 0..1023, one element each
        float x = z[bc * CTX + tid];
        float s1 = x, s2 = x * x;
#pragma unroll
        for (int off = 1; off < 64; off <<= 1) {
            s1 += __shfl_xor(s1, off);
            s2 += __shfl_xor(s2, off);
        }
        if ((tid & 63) == 0) { rr1[tid >> 6] = s1; rr2[tid >> 6] = s2; }
        __syncthreads();
        if (tid == 0) {
            float a1 = 0.f, a2 = 0.f;
            for (int k = 0; k < 16; k++) { a1 += rr1[k]; a2 += rr2[k]; }
            float m = a1 * (1.0f / CTX);
            float var = a2 * (1.0f / CTX) - m * m;
            float sd = sqrtf(var + EPS);
            meanv[bc] = m; stdv[bc] = sd;
            bcast[0] = m; bcast[1] = sd;
        }
        __syncthreads();
        float m = bcast[0], sd = bcast[1];
        float w = rw[bc % C_IN], b = rb[bc % C_IN];
        zn[bc * CTX + tid] = (x - m) / sd * w + b;
    }
}

// ---------------- dual-scale patch embed + positional -> bf16 u ----------------
__global__ void k_embed(const float* __restrict__ zn, const float* __restrict__ Wf,
                        const float* __restrict__ bfv, const float* __restrict__ Wc,
                        const float* __restrict__ bcv, const float* __restrict__ Wpos,
                        ushort* __restrict__ u) {
    int bc = blockIdx.x / TOTAL, p = blockIdx.x % TOTAL, d = threadIdx.x;
    float acc;
    if (p < NF) {
        acc = bfv[d];
        int base = p * 4;
        for (int i = 0; i < 8; i++) {
            int idx = min(base + i, CTX - 1);
            acc += zn[bc * CTX + idx] * Wf[i * DM + d];
        }
    } else {
        int pc = p - NF;
        acc = bcv[d];
        int base = pc * 16;
        for (int i = 0; i < 32; i++) {
            int idx = min(base + i, CTX - 1);
            acc += zn[bc * CTX + idx] * Wc[i * DM + d];
        }
    }
    acc += Wpos[p * DM + d];
    u[(bc * TOTAL + p) * DM + d] = f2b(acc);
}

// ---------------- bf16 MFMA GEMM: 64x64 tile (QKV and F1) ----------------
template <int GELU, int QKV>
__global__ __launch_bounds__(256) void k_gemm_mfma(const ushort* __restrict__ A,
                                                   const ushort* __restrict__ Wt,
                                                   const float* __restrict__ b0,
                                                   const float* __restrict__ b1,
                                                   const float* __restrict__ b2,
                                                   ushort* __restrict__ C,
                                                   int Mm, int N, int K) {
    __shared__ ushort As[64][40];
    __shared__ ushort Bs[64][40];
    int tid = threadIdx.x;
    int wave = tid >> 6, lane = tid & 63;
    int quad = lane >> 4, l16 = lane & 15;
    int m0 = blockIdx.y * 64, n0 = blockIdx.x * 64;

    f32x4 acc[4];
#pragma unroll
    for (int nt = 0; nt < 4; nt++) acc[nt] = (f32x4){0.f, 0.f, 0.f, 0.f};

    int row = tid >> 2, kc = (tid & 3) * 8;
    for (int k0 = 0; k0 < K; k0 += 32) {
        *(short8*)&As[row][kc] = *(const short8*)&A[(m0 + row) * K + k0 + kc];
        *(short8*)&Bs[row][kc] = *(const short8*)&Wt[(n0 + row) * K + k0 + kc];
        __syncthreads();
        short8 af = *(const short8*)&As[wave * 16 + l16][quad * 8];
#pragma unroll
        for (int nt = 0; nt < 4; nt++) {
            short8 bf = *(const short8*)&Bs[nt * 16 + l16][quad * 8];
            acc[nt] = __builtin_amdgcn_mfma_f32_16x16x32_bf16(af, bf, acc[nt], 0, 0, 0);
        }
        __syncthreads();
    }
#pragma unroll
    for (int nt = 0; nt < 4; nt++) {
        int col = n0 + nt * 16 + l16;
        float bi;
        if (QKV) {
            int bs = (n0 + nt * 16) >> 8;
            const float* bp = bs == 0 ? b0 : (bs == 1 ? b1 : b2);
            bi = bp[col & 255];
        } else {
            bi = b0[col];
        }
#pragma unroll
        for (int r = 0; r < 4; r++) {
            int rowm = m0 + wave * 16 + quad * 4 + r;
            float vv = acc[nt][r] + bi;
            if (GELU) vv = vv * 0.5f * (1.0f + erff(vv * 0.70710678118f));
            if (QKV) C[(col >> 8) * (M * DM) + rowm * DM + (col & 255)] = f2b(vv);
            else C[rowm * N + col] = f2b(vv);
        }
    }
}

// ---------------- GEMM(16x256 tile) + bias + residual + LayerNorm, in place on u ----------------
__global__ __launch_bounds__(256) void k_gemm_ln16(const ushort* __restrict__ A,
                                                   const ushort* __restrict__ Wt,
                                                   const float* __restrict__ bias,
                                                   const float* __restrict__ ls,
                                                   const float* __restrict__ lb,
                                                   ushort* __restrict__ u, int K) {
    __shared__ ushort As[16][40];
    __shared__ ushort Bs[256][40];
    __shared__ float ps1[16][4], ps2[16][4];
    int tid = threadIdx.x;
    int wave = tid >> 6, lane = tid & 63;
    int quad = lane >> 4, l16 = lane & 15;
    int m0 = blockIdx.x * 16;

    f32x4 acc[4];
#pragma unroll
    for (int nt = 0; nt < 4; nt++) acc[nt] = (f32x4){0.f, 0.f, 0.f, 0.f};

    int row = tid >> 2, kc = (tid & 3) * 8;
    for (int k0 = 0; k0 < K; k0 += 32) {
        if (tid < 64) *(short8*)&As[row][kc] = *(const short8*)&A[(m0 + row) * K + k0 + kc];
#pragma unroll
        for (int i = 0; i < 4; i++)
            *(short8*)&Bs[i * 64 + row][kc] = *(const short8*)&Wt[(i * 64 + row) * K + k0 + kc];
        __syncthreads();
        short8 af = *(const short8*)&As[l16][quad * 8];
#pragma unroll
        for (int nt = 0; nt < 4; nt++) {
            short8 bf = *(const short8*)&Bs[wave * 64 + nt * 16 + l16][quad * 8];
            acc[nt] = __builtin_amdgcn_mfma_f32_16x16x32_bf16(af, bf, acc[nt], 0, 0, 0);
        }
        __syncthreads();
    }
    float xv[4][4];
#pragma unroll
    for (int r = 0; r < 4; r++) {
        int rowg = m0 + quad * 4 + r;
        float s1 = 0.f, s2 = 0.f;
#pragma unroll
        for (int nt = 0; nt < 4; nt++) {
            int col = wave * 64 + nt * 16 + l16;
            float x = acc[nt][r] + bias[col] + bu2f(u[rowg * DM + col]);
            xv[r][nt] = x; s1 += x; s2 += x * x;
        }
        s1 += __shfl_xor(s1, 1); s2 += __shfl_xor(s2, 1);
        s1 += __shfl_xor(s1, 2); s2 += __shfl_xor(s2, 2);
        s1 += __shfl_xor(s1, 4); s2 += __shfl_xor(s2, 4);
        s1 += __shfl_xor(s1, 8); s2 += __shfl_xor(s2, 8);
        if (l16 == 0) { ps1[quad * 4 + r][wave] = s1; ps2[quad * 4 + r][wave] = s2; }
    }
    __syncthreads();
#pragma unroll
    for (int r = 0; r < 4; r++) {
        int rowl = quad * 4 + r, rowg = m0 + rowl;
        float s1 = ps1[rowl][0] + ps1[rowl][1] + ps1[rowl][2] + ps1[rowl][3];
        float s2 = ps2[rowl][0] + ps2[rowl][1] + ps2[rowl][2] + ps2[rowl][3];
        float m = s1 * (1.0f / DM);
        float var = s2 * (1.0f / DM) - m * m;
        float rs = rsqrtf(var + EPS);
#pragma unroll
        for (int nt = 0; nt < 4; nt++) {
            int col = wave * 64 + nt * 16 + l16;
            u[rowg * DM + col] = f2b((xv[r][nt] - m) * rs * ls[col] + lb[col]);
        }
    }
}

// ---------------- MFMA fused attention v5: prev prefetched into MFMA C-operand ----------------
// e = (qk + prev*4) * 0.25 = qk*SCALE + prev  (pow2 scalings exact)
template <int MODE>
__global__ __launch_bounds__(256, 4) void k_attn(const ushort* __restrict__ qm, const ushort* __restrict__ km,
                                                 const ushort* __restrict__ vm, uint4* __restrict__ sp,
                                                 ushort* __restrict__ ao) {
    __shared__ ushort sh[10240];
    uint* sh32 = (uint*)sh;
    int bh = blockIdx.x, b = bh >> 4, h = bh & 15;
    int i0 = blockIdx.y * 64;
    int t = threadIdx.x, wave = t >> 6, lane = t & 63, quad = lane >> 4, l16 = lane & 15;
    const short8 zero8 = (short8){0, 0, 0, 0, 0, 0, 0, 0};

    // issue prev-s loads FIRST: latency overlaps K/V staging + QK^T MFMAs
    int cb = (bh * 5 + (int)blockIdx.y) * 10 * 256 + t;
    uint4 pv[10];
    if (MODE) {
#pragma unroll
        for (int c = 0; c < 10; c++) pv[c] = sp[cb + c * 256];
    }

    for (int idx = t; idx < 640; idx += 256) {
        int j = idx >> 1, half = idx & 1;
        short8 kv = *(const short8*)&km[(b * TOTAL + j) * DM + h * DK + half * 8];
        int jt = j >> 4, jl = j & 15;
        *(short8*)&sh[((jt * 2 + half) * 16 + jl) * 8] = kv;
    }
    for (int idx = t; idx < 320; idx += 256) {
        int jp = idx >> 1, dh = idx & 1;
        int j = jp * 2;
        uint4 a = *(const uint4*)&vm[(b * TOTAL + j) * DM + h * DK + dh * 8];
        uint4 bb = *(const uint4*)&vm[(b * TOTAL + j + 1) * DM + h * DK + dh * 8];
        const ushort* ap = (const ushort*)&a;
        const ushort* bp = (const ushort*)&bb;
        int jr = j & 31;
        int q = (jr & 15) >> 2, jj = ((jr >> 4) << 2) + (jr & 3);
        int base = 5120 + ((j >> 5) * 4 + q) * 128 + jj;
#pragma unroll
        for (int dd = 0; dd < 8; dd++) {
            int d = dh * 8 + dd;
            uint val = (uint)ap[dd] | ((uint)bp[dd] << 16);
            sh32[(base + d * 8) >> 1] = val;
        }
    }
    short8 qf = zero8;
    if (quad < 2) qf = *(const short8*)&qm[(b * TOTAL + i0 + wave * 16 + l16) * DM + h * DK + quad * 8];
    __syncthreads();

    // init accumulators with prev*4 (or 0), then QK^T MFMAs accumulate on top
    f32x4 acc[20];
    if (MODE) {
#pragma unroll
        for (int c = 0; c < 10; c++) {
            acc[2 * c][0] = lo2f(pv[c].x) * 4.0f;
            acc[2 * c][1] = hi2f(pv[c].x) * 4.0f;
            acc[2 * c][2] = lo2f(pv[c].y) * 4.0f;
            acc[2 * c][3] = hi2f(pv[c].y) * 4.0f;
            acc[2 * c + 1][0] = lo2f(pv[c].z) * 4.0f;
            acc[2 * c + 1][1] = hi2f(pv[c].z) * 4.0f;
            acc[2 * c + 1][2] = lo2f(pv[c].w) * 4.0f;
            acc[2 * c + 1][3] = hi2f(pv[c].w) * 4.0f;
        }
    } else {
#pragma unroll
        for (int nt = 0; nt < 20; nt++) acc[nt] = (f32x4){0.f, 0.f, 0.f, 0.f};
    }
#pragma unroll
    for (int nt = 0; nt < 20; nt++) {
        short8 kf = *(const short8*)&sh[((nt * 2 + (quad & 1)) * 16 + l16) * 8];
        acc[nt] = __builtin_amdgcn_mfma_f32_16x16x32_bf16(kf, qf, acc[nt], 0, 0, 0);
    }

    // scale + s writeback
#pragma unroll
    for (int c = 0; c < 10; c++) {
        float e[8];
#pragma unroll
        for (int j = 0; j < 8; j++) e[j] = acc[2 * c + (j >> 2)][j & 3] * SCALE;
        if (MODE != 2) {
            uint4 ov;
            ov.x = pack2(e[0], e[1]); ov.y = pack2(e[2], e[3]);
            ov.z = pack2(e[4], e[5]); ov.w = pack2(e[6], e[7]);
            sp[cb + c * 256] = ov;
        }
#pragma unroll
        for (int j = 0; j < 8; j++) acc[2 * c + (j >> 2)][j & 3] = e[j];
    }

    // softmax over j: 80 in-lane + cross-quad (lanes ^16, ^32)
    float mx = -1e30f;
#pragma unroll
    for (int nt = 0; nt < 20; nt++)
#pragma unroll
        for (int r = 0; r < 4; r++) mx = fmaxf(mx, acc[nt][r]);
    mx = fmaxf(mx, __shfl_xor(mx, 16));
    mx = fmaxf(mx, __shfl_xor(mx, 32));
    float sum = 0.f;
#pragma unroll
    for (int nt = 0; nt < 20; nt++)
#pragma unroll
        for (int r = 0; r < 4; r++) { acc[nt][r] = __expf(acc[nt][r] - mx); sum += acc[nt][r]; }
    sum += __shfl_xor(sum, 16);
    sum += __shfl_xor(sum, 32);
    float inv = 1.f / sum;
#pragma unroll
    for (int nt = 0; nt < 20; nt++)
#pragma unroll
        for (int r = 0; r < 4; r++) acc[nt][r] *= inv;

    // PV: o^T = V^T P^T; B = own registers (k-permuted)
    f32x4 oacc = (f32x4){0.f, 0.f, 0.f, 0.f};
#pragma unroll
    for (int jt2 = 0; jt2 < 10; jt2++) {
        short8 vt = *(const short8*)&sh[5120 + ((jt2 * 4 + quad) * 16 + l16) * 8];
        union { short8 v; uint u[4]; } pf;
        pf.u[0] = pack2(acc[2 * jt2][0], acc[2 * jt2][1]);
        pf.u[1] = pack2(acc[2 * jt2][2], acc[2 * jt2][3]);
        pf.u[2] = pack2(acc[2 * jt2 + 1][0], acc[2 * jt2 + 1][1]);
        pf.u[3] = pack2(acc[2 * jt2 + 1][2], acc[2 * jt2 + 1][3]);
        oacc = __builtin_amdgcn_mfma_f32_16x16x32_bf16(vt, pf.v, oacc, 0, 0, 0);
    }
    us4 ov4 = (us4){f2b(oacc[0]), f2b(oacc[1]), f2b(oacc[2]), f2b(oacc[3])};
    *(us4*)&ao[(b * TOTAL + i0 + wave * 16 + l16) * DM + h * DK + quad * 4] = ov4;
}

// ---------------- head GEMM: MFMA split-K, non-atomic partials ----------------
__global__ __launch_bounds__(256) void k_head(const ushort* __restrict__ u, const ushort* __restrict__ WhT2,
                                              float* __restrict__ part) {
    int t0 = blockIdx.x * 16;
    int wave = threadIdx.x >> 6, lane = threadIdx.x & 63;
    int quad = lane >> 4, l16 = lane & 15;
    int chunk = blockIdx.y * 4 + wave;
    int kbeg = chunk * 1024;
    f32x4 acc = (f32x4){0.f, 0.f, 0.f, 0.f};
    const ushort* za = &u[(size_t)l16 * KHEAD + quad * 8];
    const ushort* wb = &WhT2[(size_t)(t0 + l16) * KHEAD + quad * 8];
#pragma unroll 4
    for (int k = kbeg; k < kbeg + 1024; k += 32) {
        short8 af = *(const short8*)&za[k];
        short8 bf = *(const short8*)&wb[k];
        acc = __builtin_amdgcn_mfma_f32_16x16x32_bf16(af, bf, acc, 0, 0, 0);
    }
#pragma unroll
    for (int r = 0; r < 4; r++)
        part[(size_t)chunk * (NB * TGT) + (quad * 4 + r) * TGT + t0 + l16] = acc[r];
}

// ---------------- final: sum 80 partials + bias + RevIN denorm ----------------
__global__ void k_final(const float* __restrict__ part, const float* __restrict__ bh,
                        const float* __restrict__ rw, const float* __restrict__ rb,
                        const float* __restrict__ meanv, const float* __restrict__ stdv,
                        float* __restrict__ out) {
    int idx = blockIdx.x * 256 + threadIdx.x;
    if (idx >= NB * TGT) return;
    int bc = idx / TGT, t = idx % TGT, c = bc % C_IN;
    float vv = bh[t];
#pragma unroll 8
    for (int j = 0; j < 80; j++) vv += part[(size_t)j * (NB * TGT) + idx];
    vv = (vv - rb[c]) / (rw[c] + EPS * EPS) * stdv[bc] + meanv[bc];
    out[idx] = vv;
}

extern "C" void kernel_launch(void* const* d_in, const int* in_sizes, int n_in,
                              void* d_out, int out_size, void* d_ws, size_t ws_size,
                              hipStream_t stream) {
    const float* z       = (const float*)d_in[0];
    const float* revin_w = (const float*)d_in[1];
    const float* revin_b = (const float*)d_in[2];
    const float* Wf      = (const float*)d_in[3];
    const float* bfv     = (const float*)d_in[4];
    const float* Wc      = (const float*)d_in[5];
    const float* bcv     = (const float*)d_in[6];
    const float* Wpos    = (const float*)d_in[7];
    const float* WQ      = (const float*)d_in[8];
    const float* bQ      = (const float*)d_in[9];
    const float* WK      = (const float*)d_in[10];
    const float* bK      = (const float*)d_in[11];
    const float* WV      = (const float*)d_in[12];
    const float* bV      = (const float*)d_in[13];
    const float* WO      = (const float*)d_in[14];
    const float* bO      = (const float*)d_in[15];
    const float* ln1s    = (const float*)d_in[16];
    const float* ln1b    = (const float*)d_in[17];
    const float* ln2s    = (const float*)d_in[18];
    const float* ln2b    = (const float*)d_in[19];
    const float* F1      = (const float*)d_in[20];
    const float* c1      = (const float*)d_in[21];
    const float* F2      = (const float*)d_in[22];
    const float* c2      = (const float*)d_in[23];
    const float* Wh      = (const float*)d_in[24];
    const float* bh      = (const float*)d_in[25];
    float* out = (float*)d_out;

    char* p = (char*)d_ws;
    float* meanv = (float*)p;    p += 16 * 4;
    float* stdv  = (float*)p;    p += 16 * 4;
    p = (char*)(((size_t)p + 255) & ~255ull);
    float* part = (float*)p;     p += (size_t)80 * NB * TGT * 4;
    float* zn = (float*)p;       p += NB * CTX * 4;
    ushort* u    = (ushort*)p;   p += (size_t)M * DM * 2;
    ushort* qkv  = (ushort*)p;   p += (size_t)3 * M * DM * 2;
    ushort* ax   = (ushort*)p;   p += (size_t)M * DM * 2;
    ushort* hbuf = (ushort*)p;   p += (size_t)M * DFF * 2;
    ushort* Wtqkv = (ushort*)p;  p += (size_t)NL * 768 * 256 * 2;
    ushort* WtO   = (ushort*)p;  p += (size_t)NL * 256 * 256 * 2;
    ushort* Ft1   = (ushort*)p;  p += (size_t)NL * 1024 * 256 * 2;
    ushort* Ft2   = (ushort*)p;  p += (size_t)NL * 256 * 1024 * 2;
    ushort* WhT2  = (ushort*)p;  p += (size_t)TGT * KHEAD * 2;
    p = (char*)(((size_t)p + 255) & ~255ull);
    uint4* sp = (uint4*)p;       p += (size_t)NB * NH * 5 * 10 * 256 * 16;  // 52.4 MB packed bf16 s

    k_prep<<<10768, dim3(32, 32), 0, stream>>>(WQ, WK, WV, WO, F1, F2, Wh,
                                               Wtqkv, WtO, Ft1, Ft2, WhT2,
                                               z, revin_w, revin_b, zn, meanv, stdv);
    k_embed<<<NB * TOTAL, 256, 0, stream>>>(zn, Wf, bfv, Wc, bcv, Wpos, u);

    for (int l = 0; l < NL; l++) {
        k_gemm_mfma<0, 1><<<dim3(12, 80), 256, 0, stream>>>(
            u, Wtqkv + (size_t)l * 768 * 256, bQ + l * DM, bK + l * DM, bV + l * DM, qkv, M, 768, 256);
        if (l == 0)
            k_attn<0><<<dim3(NB * NH, 5), 256, 0, stream>>>(qkv, qkv + M * DM, qkv + 2 * M * DM, sp, ax);
        else if (l == NL - 1)
            k_attn<2><<<dim3(NB * NH, 5), 256, 0, stream>>>(qkv, qkv + M * DM, qkv + 2 * M * DM, sp, ax);
        else
            k_attn<1><<<dim3(NB * NH, 5), 256, 0, stream>>>(qkv, qkv + M * DM, qkv + 2 * M * DM, sp, ax);
        k_gemm_ln16<<<M / 16, 256, 0, stream>>>(
            ax, WtO + (size_t)l * 65536, bO + l * DM, ln1s + l * DM, ln1b + l * DM, u, 256);
        k_gemm_mfma<1, 0><<<dim3(16, 80), 256, 0, stream>>>(
            u, Ft1 + (size_t)l * 262144, c1 + l * DFF, c1, c1, hbuf, M, 1024, 256);
        k_gemm_ln16<<<M / 16, 256, 0, stream>>>(
            hbuf, Ft2 + (size_t)l * 262144, c2 + l * DM, ln2s + l * DM, ln2b + l * DM, u, 1024);
    }

    k_head<<<dim3(TGT / 16, 20), 256, 0, stream>>>(u, WhT2, part);
    k_final<<<(NB * TGT + 255) / 256, 256, 0, stream>>>(part, bh, revin_w, revin_b, meanv, stdv, out);
}

// Round 13
// 479.511 us; speedup vs baseline: 1.0603x; 1.0603x over previous
//
#include <hip/hip_runtime.h>
#include <math.h>

typedef unsigned short ushort;
typedef unsigned int uint;
typedef __attribute__((ext_vector_type(8))) short short8;
typedef __attribute__((ext_vector_type(4))) float f32x4;
typedef __attribute__((ext_vector_type(4))) ushort us4;

constexpr int BS = 2, C_IN = 8, CTX = 1024, TGT = 96;
constexpr int DM = 256, NH = 16, DFF = 1024, NL = 4;
constexpr int NF = 256, TOTAL = 320;
constexpr int NB = 16;
constexpr int DK = 16;
constexpr float EPS = 1e-5f;
constexpr float SCALE = 0.25f;
constexpr int KHEAD = DM * TOTAL;  // 81920
constexpr int M = NB * TOTAL;      // 5120

__device__ __forceinline__ ushort f2b(float x) {
    uint u = __float_as_uint(x);
    u += 0x7fff + ((u >> 16) & 1);
    return (ushort)(u >> 16);
}
__device__ __forceinline__ float bu2f(ushort x) { return __uint_as_float(((uint)x) << 16); }
__device__ __forceinline__ float lo2f(uint p) { return __uint_as_float(p << 16); }
__device__ __forceinline__ float hi2f(uint p) { return __uint_as_float(p & 0xffff0000u); }
__device__ __forceinline__ uint pack2(float a, float b) { return (uint)f2b(a) | ((uint)f2b(b) << 16); }

// async 16B global->LDS (DMA, no VGPR round-trip). LDS dest = wave-uniform base + lane*16.
typedef __attribute__((address_space(3))) uint lds_u32;
typedef const __attribute__((address_space(1))) uint glb_u32;
__device__ __forceinline__ void ldst16(const void* g, void* l) {
    __builtin_amdgcn_global_load_lds((glb_u32*)g, (lds_u32*)l, 16, 0, 0);
}

// ---------------- weight conversions + RevIN in ONE launch; 1D grid decode ----------------
__global__ void k_prep(const float* __restrict__ WQ, const float* __restrict__ WK,
                       const float* __restrict__ WV, const float* __restrict__ WO,
                       const float* __restrict__ F1, const float* __restrict__ F2,
                       const float* __restrict__ Wh,
                       ushort* __restrict__ Wtqkv, ushort* __restrict__ WtO,
                       ushort* __restrict__ Ft1, ushort* __restrict__ Ft2,
                       ushort* __restrict__ WhT2,
                       const float* __restrict__ z, const float* __restrict__ rw,
                       const float* __restrict__ rb, float* __restrict__ zn,
                       float* __restrict__ meanv, float* __restrict__ stdv) {
    __shared__ ushort tile[32][33];
    __shared__ float rr1[16], rr2[16], bcast[2];
    int i = blockIdx.x;
    int tx = threadIdx.x, ty = threadIdx.y;
    if (i < 1024) {
        int zz = i >> 6, w = zz >> 2, l = zz & 3;
        const float* src = (w == 0 ? WQ : (w == 1 ? WK : (w == 2 ? WV : WO))) + l * 65536;
        ushort* dst = (w < 3) ? (Wtqkv + (size_t)l * 768 * 256 + w * 256 * 256)
                              : (WtO + (size_t)l * 65536);
        int c0 = (i & 7) * 32, r0 = ((i >> 3) & 7) * 32;
        tile[ty][tx] = f2b(src[(r0 + ty) * 256 + c0 + tx]);
        __syncthreads();
        dst[(c0 + ty) * 256 + r0 + tx] = tile[tx][ty];
    } else if (i < 2048) {
        int j = i - 1024, l = j >> 8;
        const float* src = F1 + (size_t)l * 262144;
        ushort* dst = Ft1 + (size_t)l * 262144;
        int c0 = (j & 31) * 32, r0 = ((j >> 5) & 7) * 32;
        tile[ty][tx] = f2b(src[(r0 + ty) * 1024 + c0 + tx]);
        __syncthreads();
        dst[(c0 + ty) * 256 + r0 + tx] = tile[tx][ty];
    } else if (i < 3072) {
        int j = i - 2048, l = j >> 8;
        const float* src = F2 + (size_t)l * 262144;
        ushort* dst = Ft2 + (size_t)l * 262144;
        int c0 = (j & 7) * 32, r0 = ((j >> 3) & 31) * 32;
        tile[ty][tx] = f2b(src[(r0 + ty) * 256 + c0 + tx]);
        __syncthreads();
        dst[(c0 + ty) * 1024 + r0 + tx] = tile[tx][ty];
    } else if (i < 10752) {
        int j = i - 3072;
        int t0 = (j % 3) * 32, rest = j / 3;
        int d0 = (rest & 7) * 32, pp = rest >> 3;
        tile[ty][tx] = f2b(Wh[((size_t)(d0 + ty) * 320 + pp) * 96 + t0 + tx]);
        __syncthreads();
        WhT2[(size_t)(t0 + ty) * KHEAD + pp * 256 + d0 + tx] = tile[tx][ty];
    } else {
        int bc = i - 10752;
        int tid = ty * 32 + tx;
        float x = z[bc * CTX + tid];
        float s1 = x, s2 = x * x;
#pragma unroll
        for (int off = 1; off < 64; off <<= 1) {
            s1 += __shfl_xor(s1, off);
            s2 += __shfl_xor(s2, off);
        }
        if ((tid & 63) == 0) { rr1[tid >> 6] = s1; rr2[tid >> 6] = s2; }
        __syncthreads();
        if (tid == 0) {
            float a1 = 0.f, a2 = 0.f;
            for (int k = 0; k < 16; k++) { a1 += rr1[k]; a2 += rr2[k]; }
            float m = a1 * (1.0f / CTX);
            float var = a2 * (1.0f / CTX) - m * m;
            float sd = sqrtf(var + EPS);
            meanv[bc] = m; stdv[bc] = sd;
            bcast[0] = m; bcast[1] = sd;
        }
        __syncthreads();
        float m = bcast[0], sd = bcast[1];
        float w = rw[bc % C_IN], b = rb[bc % C_IN];
        zn[bc * CTX + tid] = (x - m) / sd * w + b;
    }
}

// ---------------- dual-scale patch embed + positional -> bf16 u ----------------
__global__ void k_embed(const float* __restrict__ zn, const float* __restrict__ Wf,
                        const float* __restrict__ bfv, const float* __restrict__ Wc,
                        const float* __restrict__ bcv, const float* __restrict__ Wpos,
                        ushort* __restrict__ u) {
    int bc = blockIdx.x / TOTAL, p = blockIdx.x % TOTAL, d = threadIdx.x;
    float acc;
    if (p < NF) {
        acc = bfv[d];
        int base = p * 4;
        for (int i = 0; i < 8; i++) {
            int idx = min(base + i, CTX - 1);
            acc += zn[bc * CTX + idx] * Wf[i * DM + d];
        }
    } else {
        int pc = p - NF;
        acc = bcv[d];
        int base = pc * 16;
        for (int i = 0; i < 32; i++) {
            int idx = min(base + i, CTX - 1);
            acc += zn[bc * CTX + idx] * Wc[i * DM + d];
        }
    }
    acc += Wpos[p * DM + d];
    u[(bc * TOTAL + p) * DM + d] = f2b(acc);
}

// ---------------- bf16 MFMA GEMM, 64x64 tile, async LDS staging + XOR swizzle ----------------
// LDS slot (row, p) holds logical k-chunk p ^ ((row>>1)&3); frag read chunk = quad ^ ((l16>>1)&3).
template <int GELU, int QKV>
__global__ __launch_bounds__(256) void k_gemm_mfma(const ushort* __restrict__ A,
                                                   const ushort* __restrict__ Wt,
                                                   const float* __restrict__ b0,
                                                   const float* __restrict__ b1,
                                                   const float* __restrict__ b2,
                                                   ushort* __restrict__ C,
                                                   int Mm, int N, int K) {
    __shared__ ushort As[64][32];
    __shared__ ushort Bs[64][32];
    int tid = threadIdx.x;
    int wave = tid >> 6, lane = tid & 63;
    int quad = lane >> 4, l16 = lane & 15;
    int m0 = blockIdx.y * 64, n0 = blockIdx.x * 64;

    f32x4 acc[4];
#pragma unroll
    for (int nt = 0; nt < 4; nt++) acc[nt] = (f32x4){0.f, 0.f, 0.f, 0.f};

    // staging geometry: lane j of wave w fills row w*16 + (j>>2), phys chunk j&3
    int srow = wave * 16 + (lane >> 2);
    int sc = (lane & 3) ^ ((srow >> 1) & 3);            // logical k-chunk to fetch
    ushort* AsW = &As[wave * 16][0];                    // wave-uniform LDS bases
    ushort* BsW = &Bs[wave * 16][0];
    const ushort* Ag = &A[(size_t)(m0 + srow) * K + sc * 8];
    const ushort* Bg = &Wt[(size_t)(n0 + srow) * K + sc * 8];
    int rchunk = (quad ^ ((l16 >> 1) & 3)) * 8;         // frag-read phys chunk (ushort idx)

    for (int k0 = 0; k0 < K; k0 += 32) {
        ldst16(Ag + k0, AsW);
        ldst16(Bg + k0, BsW);
        __syncthreads();
        short8 af = *(const short8*)&As[wave * 16 + l16][rchunk];
#pragma unroll
        for (int nt = 0; nt < 4; nt++) {
            short8 bf = *(const short8*)&Bs[nt * 16 + l16][rchunk];
            acc[nt] = __builtin_amdgcn_mfma_f32_16x16x32_bf16(af, bf, acc[nt], 0, 0, 0);
        }
        __syncthreads();
    }
#pragma unroll
    for (int nt = 0; nt < 4; nt++) {
        int col = n0 + nt * 16 + l16;
        float bi;
        if (QKV) {
            int bs = (n0 + nt * 16) >> 8;
            const float* bp = bs == 0 ? b0 : (bs == 1 ? b1 : b2);
            bi = bp[col & 255];
        } else {
            bi = b0[col];
        }
#pragma unroll
        for (int r = 0; r < 4; r++) {
            int rowm = m0 + wave * 16 + quad * 4 + r;
            float vv = acc[nt][r] + bi;
            if (GELU) vv = vv * 0.5f * (1.0f + erff(vv * 0.70710678118f));
            if (QKV) C[(col >> 8) * (M * DM) + rowm * DM + (col & 255)] = f2b(vv);
            else C[rowm * N + col] = f2b(vv);
        }
    }
}

// ---------------- GEMM(16x256) + bias + residual + LayerNorm, async staging ----------------
__global__ __launch_bounds__(256) void k_gemm_ln16(const ushort* __restrict__ A,
                                                   const ushort* __restrict__ Wt,
                                                   const float* __restrict__ bias,
                                                   const float* __restrict__ ls,
                                                   const float* __restrict__ lb,
                                                   ushort* __restrict__ u, int K) {
    __shared__ ushort As[16][32];
    __shared__ ushort Bs[256][32];
    __shared__ float ps1[16][4], ps2[16][4];
    int tid = threadIdx.x;
    int wave = tid >> 6, lane = tid & 63;
    int quad = lane >> 4, l16 = lane & 15;
    int m0 = blockIdx.x * 16;

    f32x4 acc[4];
#pragma unroll
    for (int nt = 0; nt < 4; nt++) acc[nt] = (f32x4){0.f, 0.f, 0.f, 0.f};

    // B staging: 4 ops; op i: lane j of wave w fills row i*64 + w*16 + (j>>2), phys j&3
    int brow = wave * 16 + (lane >> 2);
    int bc_swz = (lane & 3) ^ ((brow >> 1) & 3);        // i*64 doesn't affect (row>>1)&3
    const ushort* Bg0 = &Wt[(size_t)brow * K + bc_swz * 8];
    ushort* BsW0 = &Bs[wave * 16][0];
    // A staging: wave 0 only (16 rows)
    int ar = lane >> 2;
    int ac = (lane & 3) ^ ((ar >> 1) & 3);
    const ushort* Ag = &A[(size_t)(m0 + ar) * K + ac * 8];
    int rchunk = (quad ^ ((l16 >> 1) & 3)) * 8;

    for (int k0 = 0; k0 < K; k0 += 32) {
        if (tid < 64) ldst16(Ag + k0, &As[0][0]);
#pragma unroll
        for (int i = 0; i < 4; i++)
            ldst16(Bg0 + (size_t)i * 64 * K + k0, BsW0 + i * 64 * 32);
        __syncthreads();
        short8 af = *(const short8*)&As[l16][rchunk];
#pragma unroll
        for (int nt = 0; nt < 4; nt++) {
            short8 bf = *(const short8*)&Bs[wave * 64 + nt * 16 + l16][rchunk];
            acc[nt] = __builtin_amdgcn_mfma_f32_16x16x32_bf16(af, bf, acc[nt], 0, 0, 0);
        }
        __syncthreads();
    }
    float xv[4][4];
#pragma unroll
    for (int r = 0; r < 4; r++) {
        int rowg = m0 + quad * 4 + r;
        float s1 = 0.f, s2 = 0.f;
#pragma unroll
        for (int nt = 0; nt < 4; nt++) {
            int col = wave * 64 + nt * 16 + l16;
            float x = acc[nt][r] + bias[col] + bu2f(u[rowg * DM + col]);
            xv[r][nt] = x; s1 += x; s2 += x * x;
        }
        s1 += __shfl_xor(s1, 1); s2 += __shfl_xor(s2, 1);
        s1 += __shfl_xor(s1, 2); s2 += __shfl_xor(s2, 2);
        s1 += __shfl_xor(s1, 4); s2 += __shfl_xor(s2, 4);
        s1 += __shfl_xor(s1, 8); s2 += __shfl_xor(s2, 8);
        if (l16 == 0) { ps1[quad * 4 + r][wave] = s1; ps2[quad * 4 + r][wave] = s2; }
    }
    __syncthreads();
#pragma unroll
    for (int r = 0; r < 4; r++) {
        int rowl = quad * 4 + r, rowg = m0 + rowl;
        float s1 = ps1[rowl][0] + ps1[rowl][1] + ps1[rowl][2] + ps1[rowl][3];
        float s2 = ps2[rowl][0] + ps2[rowl][1] + ps2[rowl][2] + ps2[rowl][3];
        float m = s1 * (1.0f / DM);
        float var = s2 * (1.0f / DM) - m * m;
        float rs = rsqrtf(var + EPS);
#pragma unroll
        for (int nt = 0; nt < 4; nt++) {
            int col = wave * 64 + nt * 16 + l16;
            u[rowg * DM + col] = f2b((xv[r][nt] - m) * rs * ls[col] + lb[col]);
        }
    }
}

// ---------------- MFMA fused attention v5 (unchanged from R12) ----------------
template <int MODE>
__global__ __launch_bounds__(256, 4) void k_attn(const ushort* __restrict__ qm, const ushort* __restrict__ km,
                                                 const ushort* __restrict__ vm, uint4* __restrict__ sp,
                                                 ushort* __restrict__ ao) {
    __shared__ ushort sh[10240];
    uint* sh32 = (uint*)sh;
    int bh = blockIdx.x, b = bh >> 4, h = bh & 15;
    int i0 = blockIdx.y * 64;
    int t = threadIdx.x, wave = t >> 6, lane = t & 63, quad = lane >> 4, l16 = lane & 15;
    const short8 zero8 = (short8){0, 0, 0, 0, 0, 0, 0, 0};

    int cb = (bh * 5 + (int)blockIdx.y) * 10 * 256 + t;
    uint4 pv[10];
    if (MODE) {
#pragma unroll
        for (int c = 0; c < 10; c++) pv[c] = sp[cb + c * 256];
    }

    for (int idx = t; idx < 640; idx += 256) {
        int j = idx >> 1, half = idx & 1;
        short8 kv = *(const short8*)&km[(b * TOTAL + j) * DM + h * DK + half * 8];
        int jt = j >> 4, jl = j & 15;
        *(short8*)&sh[((jt * 2 + half) * 16 + jl) * 8] = kv;
    }
    for (int idx = t; idx < 320; idx += 256) {
        int jp = idx >> 1, dh = idx & 1;
        int j = jp * 2;
        uint4 a = *(const uint4*)&vm[(b * TOTAL + j) * DM + h * DK + dh * 8];
        uint4 bb = *(const uint4*)&vm[(b * TOTAL + j + 1) * DM + h * DK + dh * 8];
        const ushort* ap = (const ushort*)&a;
        const ushort* bp = (const ushort*)&bb;
        int jr = j & 31;
        int q = (jr & 15) >> 2, jj = ((jr >> 4) << 2) + (jr & 3);
        int base = 5120 + ((j >> 5) * 4 + q) * 128 + jj;
#pragma unroll
        for (int dd = 0; dd < 8; dd++) {
            int d = dh * 8 + dd;
            uint val = (uint)ap[dd] | ((uint)bp[dd] << 16);
            sh32[(base + d * 8) >> 1] = val;
        }
    }
    short8 qf = zero8;
    if (quad < 2) qf = *(const short8*)&qm[(b * TOTAL + i0 + wave * 16 + l16) * DM + h * DK + quad * 8];
    __syncthreads();

    f32x4 acc[20];
    if (MODE) {
#pragma unroll
        for (int c = 0; c < 10; c++) {
            acc[2 * c][0] = lo2f(pv[c].x) * 4.0f;
            acc[2 * c][1] = hi2f(pv[c].x) * 4.0f;
            acc[2 * c][2] = lo2f(pv[c].y) * 4.0f;
            acc[2 * c][3] = hi2f(pv[c].y) * 4.0f;
            acc[2 * c + 1][0] = lo2f(pv[c].z) * 4.0f;
            acc[2 * c + 1][1] = hi2f(pv[c].z) * 4.0f;
            acc[2 * c + 1][2] = lo2f(pv[c].w) * 4.0f;
            acc[2 * c + 1][3] = hi2f(pv[c].w) * 4.0f;
        }
    } else {
#pragma unroll
        for (int nt = 0; nt < 20; nt++) acc[nt] = (f32x4){0.f, 0.f, 0.f, 0.f};
    }
#pragma unroll
    for (int nt = 0; nt < 20; nt++) {
        short8 kf = *(const short8*)&sh[((nt * 2 + (quad & 1)) * 16 + l16) * 8];
        acc[nt] = __builtin_amdgcn_mfma_f32_16x16x32_bf16(kf, qf, acc[nt], 0, 0, 0);
    }

#pragma unroll
    for (int c = 0; c < 10; c++) {
        float e[8];
#pragma unroll
        for (int j = 0; j < 8; j++) e[j] = acc[2 * c + (j >> 2)][j & 3] * SCALE;
        if (MODE != 2) {
            uint4 ov;
            ov.x = pack2(e[0], e[1]); ov.y = pack2(e[2], e[3]);
            ov.z = pack2(e[4], e[5]); ov.w = pack2(e[6], e[7]);
            sp[cb + c * 256] = ov;
        }
#pragma unroll
        for (int j = 0; j < 8; j++) acc[2 * c + (j >> 2)][j & 3] = e[j];
    }

    float mx = -1e30f;
#pragma unroll
    for (int nt = 0; nt < 20; nt++)
#pragma unroll
        for (int r = 0; r < 4; r++) mx = fmaxf(mx, acc[nt][r]);
    mx = fmaxf(mx, __shfl_xor(mx, 16));
    mx = fmaxf(mx, __shfl_xor(mx, 32));
    float sum = 0.f;
#pragma unroll
    for (int nt = 0; nt < 20; nt++)
#pragma unroll
        for (int r = 0; r < 4; r++) { acc[nt][r] = __expf(acc[nt][r] - mx); sum += acc[nt][r]; }
    sum += __shfl_xor(sum, 16);
    sum += __shfl_xor(sum, 32);
    float inv = 1.f / sum;
#pragma unroll
    for (int nt = 0; nt < 20; nt++)
#pragma unroll
        for (int r = 0; r < 4; r++) acc[nt][r] *= inv;

    f32x4 oacc = (f32x4){0.f, 0.f, 0.f, 0.f};
#pragma unroll
    for (int jt2 = 0; jt2 < 10; jt2++) {
        short8 vt = *(const short8*)&sh[5120 + ((jt2 * 4 + quad) * 16 + l16) * 8];
        union { short8 v; uint u[4]; } pf;
        pf.u[0] = pack2(acc[2 * jt2][0], acc[2 * jt2][1]);
        pf.u[1] = pack2(acc[2 * jt2][2], acc[2 * jt2][3]);
        pf.u[2] = pack2(acc[2 * jt2 + 1][0], acc[2 * jt2 + 1][1]);
        pf.u[3] = pack2(acc[2 * jt2 + 1][2], acc[2 * jt2 + 1][3]);
        oacc = __builtin_amdgcn_mfma_f32_16x16x32_bf16(vt, pf.v, oacc, 0, 0, 0);
    }
    us4 ov4 = (us4){f2b(oacc[0]), f2b(oacc[1]), f2b(oacc[2]), f2b(oacc[3])};
    *(us4*)&ao[(b * TOTAL + i0 + wave * 16 + l16) * DM + h * DK + quad * 4] = ov4;
}

// ---------------- head GEMM: MFMA split-K, non-atomic partials ----------------
__global__ __launch_bounds__(256) void k_head(const ushort* __restrict__ u, const ushort* __restrict__ WhT2,
                                              float* __restrict__ part) {
    int t0 = blockIdx.x * 16;
    int wave = threadIdx.x >> 6, lane = threadIdx.x & 63;
    int quad = lane >> 4, l16 = lane & 15;
    int chunk = blockIdx.y * 4 + wave;
    int kbeg = chunk * 1024;
    f32x4 acc = (f32x4){0.f, 0.f, 0.f, 0.f};
    const ushort* za = &u[(size_t)l16 * KHEAD + quad * 8];
    const ushort* wb = &WhT2[(size_t)(t0 + l16) * KHEAD + quad * 8];
#pragma unroll 4
    for (int k = kbeg; k < kbeg + 1024; k += 32) {
        short8 af = *(const short8*)&za[k];
        short8 bf = *(const short8*)&wb[k];
        acc = __builtin_amdgcn_mfma_f32_16x16x32_bf16(af, bf, acc, 0, 0, 0);
    }
#pragma unroll
    for (int r = 0; r < 4; r++)
        part[(size_t)chunk * (NB * TGT) + (quad * 4 + r) * TGT + t0 + l16] = acc[r];
}

// ---------------- final: sum 80 partials + bias + RevIN denorm ----------------
__global__ void k_final(const float* __restrict__ part, const float* __restrict__ bh,
                        const float* __restrict__ rw, const float* __restrict__ rb,
                        const float* __restrict__ meanv, const float* __restrict__ stdv,
                        float* __restrict__ out) {
    int idx = blockIdx.x * 256 + threadIdx.x;
    if (idx >= NB * TGT) return;
    int bc = idx / TGT, t = idx % TGT, c = bc % C_IN;
    float vv = bh[t];
#pragma unroll 8
    for (int j = 0; j < 80; j++) vv += part[(size_t)j * (NB * TGT) + idx];
    vv = (vv - rb[c]) / (rw[c] + EPS * EPS) * stdv[bc] + meanv[bc];
    out[idx] = vv;
}

extern "C" void kernel_launch(void* const* d_in, const int* in_sizes, int n_in,
                              void* d_out, int out_size, void* d_ws, size_t ws_size,
                              hipStream_t stream) {
    const float* z       = (const float*)d_in[0];
    const float* revin_w = (const float*)d_in[1];
    const float* revin_b = (const float*)d_in[2];
    const float* Wf      = (const float*)d_in[3];
    const float* bfv     = (const float*)d_in[4];
    const float* Wc      = (const float*)d_in[5];
    const float* bcv     = (const float*)d_in[6];
    const float* Wpos    = (const float*)d_in[7];
    const float* WQ      = (const float*)d_in[8];
    const float* bQ      = (const float*)d_in[9];
    const float* WK      = (const float*)d_in[10];
    const float* bK      = (const float*)d_in[11];
    const float* WV      = (const float*)d_in[12];
    const float* bV      = (const float*)d_in[13];
    const float* WO      = (const float*)d_in[14];
    const float* bO      = (const float*)d_in[15];
    const float* ln1s    = (const float*)d_in[16];
    const float* ln1b    = (const float*)d_in[17];
    const float* ln2s    = (const float*)d_in[18];
    const float* ln2b    = (const float*)d_in[19];
    const float* F1      = (const float*)d_in[20];
    const float* c1      = (const float*)d_in[21];
    const float* F2      = (const float*)d_in[22];
    const float* c2      = (const float*)d_in[23];
    const float* Wh      = (const float*)d_in[24];
    const float* bh      = (const float*)d_in[25];
    float* out = (float*)d_out;

    char* p = (char*)d_ws;
    float* meanv = (float*)p;    p += 16 * 4;
    float* stdv  = (float*)p;    p += 16 * 4;
    p = (char*)(((size_t)p + 255) & ~255ull);
    float* part = (float*)p;     p += (size_t)80 * NB * TGT * 4;
    float* zn = (float*)p;       p += NB * CTX * 4;
    ushort* u    = (ushort*)p;   p += (size_t)M * DM * 2;
    ushort* qkv  = (ushort*)p;   p += (size_t)3 * M * DM * 2;
    ushort* ax   = (ushort*)p;   p += (size_t)M * DM * 2;
    ushort* hbuf = (ushort*)p;   p += (size_t)M * DFF * 2;
    ushort* Wtqkv = (ushort*)p;  p += (size_t)NL * 768 * 256 * 2;
    ushort* WtO   = (ushort*)p;  p += (size_t)NL * 256 * 256 * 2;
    ushort* Ft1   = (ushort*)p;  p += (size_t)NL * 1024 * 256 * 2;
    ushort* Ft2   = (ushort*)p;  p += (size_t)NL * 256 * 1024 * 2;
    ushort* WhT2  = (ushort*)p;  p += (size_t)TGT * KHEAD * 2;
    p = (char*)(((size_t)p + 255) & ~255ull);
    uint4* sp = (uint4*)p;       p += (size_t)NB * NH * 5 * 10 * 256 * 16;  // 52.4 MB packed bf16 s

    k_prep<<<10768, dim3(32, 32), 0, stream>>>(WQ, WK, WV, WO, F1, F2, Wh,
                                               Wtqkv, WtO, Ft1, Ft2, WhT2,
                                               z, revin_w, revin_b, zn, meanv, stdv);
    k_embed<<<NB * TOTAL, 256, 0, stream>>>(zn, Wf, bfv, Wc, bcv, Wpos, u);

    for (int l = 0; l < NL; l++) {
        k_gemm_mfma<0, 1><<<dim3(12, 80), 256, 0, stream>>>(
            u, Wtqkv + (size_t)l * 768 * 256, bQ + l * DM, bK + l * DM, bV + l * DM, qkv, M, 768, 256);
        if (l == 0)
            k_attn<0><<<dim3(NB * NH, 5), 256, 0, stream>>>(qkv, qkv + M * DM, qkv + 2 * M * DM, sp, ax);
        else if (l == NL - 1)
            k_attn<2><<<dim3(NB * NH, 5), 256, 0, stream>>>(qkv, qkv + M * DM, qkv + 2 * M * DM, sp, ax);
        else
            k_attn<1><<<dim3(NB * NH, 5), 256, 0, stream>>>(qkv, qkv + M * DM, qkv + 2 * M * DM, sp, ax);
        k_gemm_ln16<<<M / 16, 256, 0, stream>>>(
            ax, WtO + (size_t)l * 65536, bO + l * DM, ln1s + l * DM, ln1b + l * DM, u, 256);
        k_gemm_mfma<1, 0><<<dim3(16, 80), 256, 0, stream>>>(
            u, Ft1 + (size_t)l * 262144, c1 + l * DFF, c1, c1, hbuf, M, 1024, 256);
        k_gemm_ln16<<<M / 16, 256, 0, stream>>>(
            hbuf, Ft2 + (size_t)l * 262144, c2 + l * DM, ln2s + l * DM, ln2b + l * DM, u, 1024);
    }

    k_head<<<dim3(TGT / 16, 20), 256, 0, stream>>>(u, WhT2, part);
    k_final<<<(NB * TGT + 255) / 256, 256, 0, stream>>>(part, bh, revin_w, revin_b, meanv, stdv, out);
}